// Round 10
// baseline (200.875 us; speedup 1.0000x reference)
//
#include <hip/hip_runtime.h>

namespace {
constexpr int NN  = 100000;   // nodes
constexpr int NE  = 1000000;  // edges
constexpr int INF = 256;
constexpr int HF  = 64;
constexpr int OF  = 16;
constexpr int SCAN_CHUNK = 1024;                       // elems per scan block (256 thr x 4)
constexpr int NBLK = (NN + SCAN_CHUNK - 1) / SCAN_CHUNK; // 98
constexpr int NSEG = 8;       // dst segments, pinned to XCDs via blockIdx%8
constexpr int SEGW = (NN + NSEG - 1) / NSEG;             // 12500 nodes / segment
constexpr int CNTW = 100096;  // padded cnt/cursor width (ints)
constexpr int ZBLK = (CNTW / 4 + 255) / 256;             // 98 zero-blocks
constexpr int CAP  = 131072;  // per-segment edge capacity (seed-0 counts ~125k)
constexpr int HSBLK = NSEG * (CAP / 256);                // 4096 blocks for hist/scatter
}

typedef __attribute__((ext_vector_type(8))) short     sh8;
typedef __attribute__((ext_vector_type(4))) float     f32x4;
typedef __attribute__((ext_vector_type(8))) unsigned short us8;

__device__ __forceinline__ unsigned short f2bf(float f) {
    unsigned int u = __builtin_bit_cast(unsigned int, f);
    u += 0x7FFFu + ((u >> 16) & 1u);       // round-to-nearest-even
    return (unsigned short)(u >> 16);
}
__device__ __forceinline__ float bf2f(unsigned short s) {
    return __builtin_bit_cast(float, (unsigned int)s << 16);
}

// ---- pre: zero cnt + segcnt + W1 -> bf16 transposed, one launch ------------
__global__ void k_pre(int* __restrict__ cnt, const float* __restrict__ W1,
                      unsigned short* __restrict__ wt_g, int* __restrict__ segcnt) {
    int b = blockIdx.x, t = threadIdx.x;
    if (b < ZBLK) {
        int i = (b * 256 + t) * 4;
        if (i < CNTW) *(int4*)(cnt + i) = (int4){0, 0, 0, 0};
    } else {
        if (b == ZBLK && t < NSEG) segcnt[t] = 0;
        int idx = (b - ZBLK) * 256 + t;       // 16384 tasks
        int c = idx >> 8, k = idx & 255;
        wt_g[idx] = f2bf(W1[(size_t)k * HF + c]);
    }
}

// ---- partition: read edges ONCE, bin by dst-segment into segbuf ------------
// 1024 threads/block: LDS rank-atomics + only 8 global cursor atomics/block.
__global__ __launch_bounds__(1024) void k_part(const int* __restrict__ src,
                                               const int* __restrict__ dst,
                                               int2* __restrict__ segbuf,
                                               int* __restrict__ segcnt) {
    __shared__ int cnt8[NSEG];
    __shared__ int base8[NSEG];
    int t = threadIdx.x;
    if (t < NSEG) cnt8[t] = 0;
    __syncthreads();
    int e = blockIdx.x * 1024 + t;
    int s = 0, d = 0, seg = 0, rank = 0;
    bool ok = e < NE;
    if (ok) {
        s = src[e]; d = dst[e];
        seg = (unsigned)d / (unsigned)SEGW;
        rank = atomicAdd(&cnt8[seg], 1);
    }
    __syncthreads();
    if (t < NSEG) base8[t] = atomicAdd(&segcnt[t], cnt8[t]);
    __syncthreads();
    if (ok) segbuf[seg * CAP + base8[seg] + rank] = make_int2(s, d);
}

// ---- degree histogram over compacted segment slices (XCD-pinned) -----------
__global__ __launch_bounds__(256) void k_hist(const int2* __restrict__ segbuf,
                                              const int* __restrict__ segcnt,
                                              int* __restrict__ cnt) {
    int b   = blockIdx.x;
    int seg = b & (NSEG - 1);
    int i   = (b >> 3) * 256 + threadIdx.x;
    if (i < segcnt[seg]) {
        int d = segbuf[seg * CAP + i].y;
        atomicAdd(&cnt[d], 1);
    }
}

// ---- block-reduce of cnt -> bsum, fused dinv = rsqrt(cnt+1) ----------------
__global__ __launch_bounds__(256) void k_reduce(const int* __restrict__ cnt,
                                                int* __restrict__ bsum,
                                                float* __restrict__ dinv) {
    int t = threadIdx.x;
    int i0 = blockIdx.x * SCAN_CHUNK + t * 4;
    int s = 0;
    float dv[4] = {0.f, 0.f, 0.f, 0.f};
    #pragma unroll
    for (int q = 0; q < 4; ++q) {
        if (i0 + q < NN) {
            int c = cnt[i0 + q];
            s += c;
            dv[q] = rsqrtf((float)(c + 1));
        }
    }
    if (i0 + 3 < NN) *(float4*)(dinv + i0) = (float4){dv[0], dv[1], dv[2], dv[3]};
    else { for (int q = 0; q < 4; ++q) if (i0 + q < NN) dinv[i0 + q] = dv[q]; }
    #pragma unroll
    for (int off = 32; off > 0; off >>= 1) s += __shfl_down(s, off);
    __shared__ int wsum[4];
    int lane = t & 63, wid = t >> 6;
    if (lane == 0) wsum[wid] = s;
    __syncthreads();
    if (t == 0) bsum[blockIdx.x] = wsum[0] + wsum[1] + wsum[2] + wsum[3];
}

// ---- wave-parallel exclusive scan of bsum[98] ------------------------------
__global__ void k_partials(int* __restrict__ bsum) {
    int l = threadIdx.x;   // 64 threads
    int a0 = (l < NBLK) ? bsum[l] : 0;
    int b0 = (64 + l < NBLK) ? bsum[64 + l] : 0;
    int a = a0, b = b0;
    #pragma unroll
    for (int off = 1; off < 64; off <<= 1) {
        int na = __shfl_up(a, off); if (l >= off) a += na;
        int nb = __shfl_up(b, off); if (l >= off) b += nb;
    }
    int tot = __shfl(a, 63);
    if (l < NBLK) bsum[l] = a - a0;
    if (64 + l < NBLK) bsum[64 + l] = tot + b - b0;
}

__global__ __launch_bounds__(256) void k_scan(const int* __restrict__ cnt,
                                              const int* __restrict__ bsum,
                                              int* __restrict__ rowptr,
                                              int* __restrict__ cursor) {
    int t = threadIdx.x;
    int i0 = blockIdx.x * SCAN_CHUNK + t * 4;
    int v0 = 0, v1 = 0, v2 = 0, v3 = 0;
    if (i0 + 0 < NN) v0 = cnt[i0 + 0];
    if (i0 + 1 < NN) v1 = cnt[i0 + 1];
    if (i0 + 2 < NN) v2 = cnt[i0 + 2];
    if (i0 + 3 < NN) v3 = cnt[i0 + 3];
    int tsum = v0 + v1 + v2 + v3;
    int lane = t & 63, wid = t >> 6;
    int incl = tsum;
    #pragma unroll
    for (int off = 1; off < 64; off <<= 1) {
        int n = __shfl_up(incl, off);
        if (lane >= off) incl += n;
    }
    __shared__ int wsum[4];
    if (lane == 63) wsum[wid] = incl;
    __syncthreads();
    int woff = 0;
    for (int w = 0; w < wid; ++w) woff += wsum[w];
    int excl = woff + (incl - tsum) + bsum[blockIdx.x];
    int e0 = excl, e1 = e0 + v0, e2 = e1 + v1, e3 = e2 + v2;
    if (i0 + 0 < NN) { rowptr[i0 + 0] = e0; cursor[i0 + 0] = e0; }
    if (i0 + 1 < NN) { rowptr[i0 + 1] = e1; cursor[i0 + 1] = e1; }
    if (i0 + 2 < NN) { rowptr[i0 + 2] = e2; cursor[i0 + 2] = e2; }
    if (i0 + 3 < NN) { rowptr[i0 + 3] = e3; cursor[i0 + 3] = e3; }
    if (i0 + 3 == NN - 1) rowptr[NN] = e3 + v3;
}

// ---- scatter over compacted segment slices (XCD-pinned) --------------------
__global__ __launch_bounds__(256) void k_scatter(const int2* __restrict__ segbuf,
                                                 const int* __restrict__ segcnt,
                                                 int* __restrict__ cursor,
                                                 int* __restrict__ eidx) {
    int b   = blockIdx.x;
    int seg = b & (NSEG - 1);
    int i   = (b >> 3) * 256 + threadIdx.x;
    if (i < segcnt[seg]) {
        int2 ed = segbuf[seg * CAP + i];
        int p = atomicAdd(&cursor[ed.y], 1);
        eidx[p] = ed.x;
    }
}

// ---- GEMM1: h1(bf16) = x @ W1  [NN,256]x[256,64], bf16 MFMA ----------------
__global__ __launch_bounds__(256, 4) void k_gemm1(const float* __restrict__ x,
                                                  const unsigned short* __restrict__ wt_g,
                                                  unsigned short* __restrict__ h1) {
    __shared__ unsigned short wt[64 * 264];    // stride 264: 2-way bank alias (free)
    int t = threadIdx.x;
    int w = t >> 6, l = t & 63;
    int row0 = blockIdx.x * 128;

    #pragma unroll
    for (int p = 0; p < 8; ++p) {
        int T   = p * 256 + t;
        int c   = T >> 5;
        int kb8 = T & 31;
        *(us8*)(wt + c * 264 + kb8 * 8) = *(const us8*)(wt_g + c * 256 + kb8 * 8);
    }
    __syncthreads();

    int m = l & 15;
    int g = l >> 4;
    int gr0 = row0 + w * 32 + m;      if (gr0 > NN - 1) gr0 = NN - 1;
    int gr1 = row0 + w * 32 + 16 + m; if (gr1 > NN - 1) gr1 = NN - 1;
    const float* p0 = x + (size_t)gr0 * INF + g * 8;
    const float* p1 = x + (size_t)gr1 * INF + g * 8;

    f32x4 acc[2][4];
    #pragma unroll
    for (int i = 0; i < 2; ++i)
        #pragma unroll
        for (int j = 0; j < 4; ++j) acc[i][j] = (f32x4){0.f, 0.f, 0.f, 0.f};

    #pragma unroll 2
    for (int kb = 0; kb < INF; kb += 32) {
        float4 u0 = *(const float4*)(p0 + kb);
        float4 u1 = *(const float4*)(p0 + kb + 4);
        float4 u2 = *(const float4*)(p1 + kb);
        float4 u3 = *(const float4*)(p1 + kb + 4);
        us8 a0u = { f2bf(u0.x), f2bf(u0.y), f2bf(u0.z), f2bf(u0.w),
                    f2bf(u1.x), f2bf(u1.y), f2bf(u1.z), f2bf(u1.w) };
        us8 a1u = { f2bf(u2.x), f2bf(u2.y), f2bf(u2.z), f2bf(u2.w),
                    f2bf(u3.x), f2bf(u3.y), f2bf(u3.z), f2bf(u3.w) };
        sh8 a0 = __builtin_bit_cast(sh8, a0u);
        sh8 a1 = __builtin_bit_cast(sh8, a1u);
        #pragma unroll
        for (int nt = 0; nt < 4; ++nt) {
            sh8 b = *(const sh8*)(wt + (nt * 16 + m) * 264 + kb + g * 8);
            acc[0][nt] = __builtin_amdgcn_mfma_f32_16x16x32_bf16(a0, b, acc[0][nt], 0, 0, 0);
            acc[1][nt] = __builtin_amdgcn_mfma_f32_16x16x32_bf16(a1, b, acc[1][nt], 0, 0, 0);
        }
    }

    #pragma unroll
    for (int mt = 0; mt < 2; ++mt) {
        #pragma unroll
        for (int r = 0; r < 4; ++r) {
            int gr = row0 + w * 32 + mt * 16 + (l >> 4) * 4 + r;
            if (gr < NN) {
                #pragma unroll
                for (int nt = 0; nt < 4; ++nt)
                    h1[(size_t)gr * HF + nt * 16 + (l & 15)] = f2bf(acc[mt][nt][r]);
            }
        }
    }
}

// ---- Gather layer 1: 8 nodes/wave, 8 lanes/node, lane owns 8 feats ---------
__global__ __launch_bounds__(256) void k_gather1(const int* __restrict__ rowptr,
                                                 const int* __restrict__ eidx,
                                                 const float* __restrict__ dinv,
                                                 const unsigned short* __restrict__ h1,
                                                 const float* __restrict__ b1,
                                                 const float* __restrict__ W2,
                                                 float* __restrict__ h2) {
    __shared__ float w2L[HF * OF];     // 4KB, [k][j]
    __shared__ float hrL[32][HF + 4];  // 8.5KB, stride 68 (bank-spread)
    int t = threadIdx.x;
    *(float4*)(w2L + t * 4) = *(const float4*)(W2 + t * 4);   // 256*4 = 1024 ✓

    int nodeL = t >> 3;           // 0..31: node within block
    int fg    = t & 7;            // feature octet: feats fg*8..fg*8+7
    int v     = blockIdx.x * 32 + nodeL;   // NN = 3125*32 exact
    int beg = rowptr[v], end = rowptr[v + 1];

    float acc[8] = {};
    for (int i = beg; i < end; ++i) {
        int s = eidx[i];                      // broadcast across the 8 lanes
        float wgt = dinv[s];
        us8 hv = *(const us8*)(h1 + (size_t)s * HF + fg * 8);
        #pragma unroll
        for (int q = 0; q < 8; ++q) acc[q] += wgt * bf2f(hv[q]);
    }

    {
        float dv = dinv[v], sl = dv * dv;
        us8 hv = *(const us8*)(h1 + (size_t)v * HF + fg * 8);
        #pragma unroll
        for (int q = 0; q < 8; ++q) {
            float val = dv * acc[q] + sl * bf2f(hv[q]) + b1[fg * 8 + q];
            hrL[nodeL][fg * 8 + q] = val > 0.f ? val : 0.f;
        }
    }
    __syncthreads();

    #pragma unroll
    for (int T = t; T < 512; T += 256) {
        int n = T >> 4, j = T & 15;
        const float* hr = hrL[n];
        float p = 0.f;
        #pragma unroll
        for (int k = 0; k < HF; ++k) p += hr[k] * w2L[k * OF + j];
        h2[(size_t)(blockIdx.x * 32 + n) * OF + j] = p;
    }
}

// ---- Gather layer 2 (fused self-loop + bias) -------------------------------
__global__ __launch_bounds__(256) void k_gather2(const int* __restrict__ rowptr,
                                                 const int* __restrict__ eidx,
                                                 const float* __restrict__ dinv,
                                                 const float* __restrict__ h2,
                                                 const float* __restrict__ b2,
                                                 float* __restrict__ out) {
    int gid   = blockIdx.x * 256 + threadIdx.x;
    int v     = gid >> 6;
    int lane  = threadIdx.x & 63;
    int eslot = lane >> 2;        // 0..15
    int fg    = lane & 3;         // float4 group
    int beg = rowptr[v], end = rowptr[v + 1];
    float4 acc = {0.f, 0.f, 0.f, 0.f};
    for (int i = beg + eslot; i < end; i += 16) {
        int s = eidx[i];
        float w = dinv[s];
        float4 hv = *(const float4*)(h2 + (size_t)s * OF + fg * 4);
        acc.x += w * hv.x; acc.y += w * hv.y; acc.z += w * hv.z; acc.w += w * hv.w;
    }
    #pragma unroll
    for (int m = 4; m <= 32; m <<= 1) {
        acc.x += __shfl_xor(acc.x, m);
        acc.y += __shfl_xor(acc.y, m);
        acc.z += __shfl_xor(acc.z, m);
        acc.w += __shfl_xor(acc.w, m);
    }
    if (eslot == 0) {
        float dv = dinv[v];
        float sl = dv * dv;
        float4 hv = *(const float4*)(h2 + (size_t)v * OF + fg * 4);
        float4 bv = *(const float4*)(b2 + fg * 4);
        float4 o;
        o.x = dv * acc.x + sl * hv.x + bv.x;
        o.y = dv * acc.y + sl * hv.y + bv.y;
        o.z = dv * acc.z + sl * hv.z + bv.z;
        o.w = dv * acc.w + sl * hv.w + bv.w;
        *(float4*)(out + (size_t)v * OF + fg * 4) = o;
    }
}

extern "C" void kernel_launch(void* const* d_in, const int* in_sizes, int n_in,
                              void* d_out, int out_size, void* d_ws, size_t ws_size,
                              hipStream_t stream) {
    const float* x   = (const float*)d_in[0];
    const int*   ei  = (const int*)d_in[1];
    const int*   src = ei;            // edge_index[0]
    const int*   dst = ei + NE;       // edge_index[1]
    const float* W1  = (const float*)d_in[2];
    const float* b1  = (const float*)d_in[3];
    const float* W2  = (const float*)d_in[4];
    const float* b2  = (const float*)d_in[5];
    float* out = (float*)d_out;

    // workspace layout (4B units unless noted)
    float* dinv  = (float*)d_ws;                           // [CNTW]
    unsigned short* h1b = (unsigned short*)(dinv + CNTW);  // [NN*64] bf16 (3.2M ints)
    float* h2    = (float*)(h1b + (size_t)NN * HF);        // [NN*16]
    int*   cnt   = (int*)(h2 + (size_t)NN * OF);           // [CNTW]
    int*   rowptr = cnt + CNTW;                            // [100352]
    int*   cursor = rowptr + 100352;                       // [CNTW]
    int*   eidx  = cursor + CNTW;                          // [NE]
    int*   bsum  = eidx + NE;                              // [128]
    unsigned short* wt_g = (unsigned short*)(bsum + 128);  // [64*256] bf16 (8192 ints)
    int*   segcnt = (int*)(wt_g + 64 * 256);               // [8]
    int2*  segbuf = (int2*)(segcnt + 8);                   // [8*CAP] int2 (8.4MB)

    // CSR build + norms + W pre-transpose
    k_pre<<<ZBLK + 64, 256, 0, stream>>>(cnt, W1, wt_g, segcnt);
    k_part<<<(NE + 1023) / 1024, 1024, 0, stream>>>(src, dst, segbuf, segcnt);
    k_hist<<<HSBLK, 256, 0, stream>>>(segbuf, segcnt, cnt);
    k_reduce<<<NBLK, 256, 0, stream>>>(cnt, bsum, dinv);
    k_partials<<<1, 64, 0, stream>>>(bsum);
    k_scan<<<NBLK, 256, 0, stream>>>(cnt, bsum, rowptr, cursor);
    k_scatter<<<HSBLK, 256, 0, stream>>>(segbuf, segcnt, cursor, eidx);

    // layer 1 (+ fused layer-2 GEMM)
    k_gemm1<<<(NN + 127) / 128, 256, 0, stream>>>(x, wt_g, h1b);
    k_gather1<<<NN / 32, 256, 0, stream>>>(rowptr, eidx, dinv, h1b, b1, W2, h2);

    // layer 2 aggregation
    k_gather2<<<(NN * HF) / 256, 256, 0, stream>>>(rowptr, eidx, dinv, h2, b2, out);
}

// Round 11
// 191.204 us; speedup vs baseline: 1.0506x; 1.0506x over previous
//
#include <hip/hip_runtime.h>

namespace {
constexpr int NN  = 100000;   // nodes
constexpr int NE  = 1000000;  // edges
constexpr int INF = 256;
constexpr int HF  = 64;
constexpr int OF  = 16;
constexpr int SCAN_CHUNK = 1024;                       // elems per scan block (256 thr x 4)
constexpr int NBLK = (NN + SCAN_CHUNK - 1) / SCAN_CHUNK; // 98
constexpr int NSEG = 8;       // dst segments, pinned to XCDs via blockIdx%8
constexpr int SEGW = (NN + NSEG - 1) / NSEG;             // 12500 nodes / segment
constexpr int CNTW = 100096;  // padded cnt/cursor width (ints)
constexpr int ZBLK = (CNTW / 4 + 255) / 256;             // 98 zero-blocks
}

typedef __attribute__((ext_vector_type(8))) short     sh8;
typedef __attribute__((ext_vector_type(4))) float     f32x4;
typedef __attribute__((ext_vector_type(8))) unsigned short us8;

__device__ __forceinline__ unsigned short f2bf(float f) {
    unsigned int u = __builtin_bit_cast(unsigned int, f);
    u += 0x7FFFu + ((u >> 16) & 1u);       // round-to-nearest-even
    return (unsigned short)(u >> 16);
}
__device__ __forceinline__ float bf2f(unsigned short s) {
    return __builtin_bit_cast(float, (unsigned int)s << 16);
}

// ---- pre: zero cnt + W1 -> bf16 transposed, one launch ---------------------
__global__ void k_pre(int* __restrict__ cnt, const float* __restrict__ W1,
                      unsigned short* __restrict__ wt_g) {
    int b = blockIdx.x, t = threadIdx.x;
    if (b < ZBLK) {
        int i = (b * 256 + t) * 4;
        if (i < CNTW) *(int4*)(cnt + i) = (int4){0, 0, 0, 0};
    } else {
        int idx = (b - ZBLK) * 256 + t;       // 16384 tasks
        int c = idx >> 8, k = idx & 255;
        wt_g[idx] = f2bf(W1[(size_t)k * HF + c]);
    }
}

// ---- degree histogram (int), XCD-pinned dst segments -----------------------
__global__ void k_hist(const int* __restrict__ dst, int* __restrict__ cnt) {
    int b     = blockIdx.x;
    int seg   = b & (NSEG - 1);
    int chunk = b >> 3;
    int e = chunk * 256 + threadIdx.x;
    if (e < NE) {
        int d = dst[e];
        if ((unsigned)d / (unsigned)SEGW == (unsigned)seg)
            atomicAdd(&cnt[d], 1);
    }
}

// ---- block-reduce of cnt -> bsum, fused dinv = rsqrt(cnt+1) ----------------
__global__ __launch_bounds__(256) void k_reduce(const int* __restrict__ cnt,
                                                int* __restrict__ bsum,
                                                float* __restrict__ dinv) {
    int t = threadIdx.x;
    int i0 = blockIdx.x * SCAN_CHUNK + t * 4;
    int s = 0;
    float dv[4] = {0.f, 0.f, 0.f, 0.f};
    #pragma unroll
    for (int q = 0; q < 4; ++q) {
        if (i0 + q < NN) {
            int c = cnt[i0 + q];
            s += c;
            dv[q] = rsqrtf((float)(c + 1));
        }
    }
    if (i0 + 3 < NN) *(float4*)(dinv + i0) = (float4){dv[0], dv[1], dv[2], dv[3]};
    else { for (int q = 0; q < 4; ++q) if (i0 + q < NN) dinv[i0 + q] = dv[q]; }
    #pragma unroll
    for (int off = 32; off > 0; off >>= 1) s += __shfl_down(s, off);
    __shared__ int wsum[4];
    int lane = t & 63, wid = t >> 6;
    if (lane == 0) wsum[wid] = s;
    __syncthreads();
    if (t == 0) bsum[blockIdx.x] = wsum[0] + wsum[1] + wsum[2] + wsum[3];
}

// ---- scan: each block derives its own prefix from bsum (no partials pass) --
__global__ __launch_bounds__(256) void k_scan(const int* __restrict__ cnt,
                                              const int* __restrict__ bsum,
                                              int* __restrict__ rowptr,
                                              int* __restrict__ cursor) {
    int t = threadIdx.x;
    int b = blockIdx.x;
    int lane = t & 63, wid = t >> 6;

    // per-wave: exclusive prefix of bsum[0..b-1] (NBLK=98 entries, L2-hot)
    int p = 0;
    if (lane < b) p += bsum[lane];
    if (64 + lane < b) p += bsum[64 + lane];
    #pragma unroll
    for (int off = 32; off > 0; off >>= 1) p += __shfl_down(p, off);
    int blockBase = __shfl(p, 0);

    int i0 = b * SCAN_CHUNK + t * 4;
    int v0 = 0, v1 = 0, v2 = 0, v3 = 0;
    if (i0 + 0 < NN) v0 = cnt[i0 + 0];
    if (i0 + 1 < NN) v1 = cnt[i0 + 1];
    if (i0 + 2 < NN) v2 = cnt[i0 + 2];
    if (i0 + 3 < NN) v3 = cnt[i0 + 3];
    int tsum = v0 + v1 + v2 + v3;
    int incl = tsum;
    #pragma unroll
    for (int off = 1; off < 64; off <<= 1) {
        int n = __shfl_up(incl, off);
        if (lane >= off) incl += n;
    }
    __shared__ int wsum[4];
    if (lane == 63) wsum[wid] = incl;
    __syncthreads();
    int woff = 0;
    for (int w = 0; w < wid; ++w) woff += wsum[w];
    int excl = woff + (incl - tsum) + blockBase;
    int e0 = excl, e1 = e0 + v0, e2 = e1 + v1, e3 = e2 + v2;
    if (i0 + 0 < NN) { rowptr[i0 + 0] = e0; cursor[i0 + 0] = e0; }
    if (i0 + 1 < NN) { rowptr[i0 + 1] = e1; cursor[i0 + 1] = e1; }
    if (i0 + 2 < NN) { rowptr[i0 + 2] = e2; cursor[i0 + 2] = e2; }
    if (i0 + 3 < NN) { rowptr[i0 + 3] = e3; cursor[i0 + 3] = e3; }
    if (i0 + 3 == NN - 1) rowptr[NN] = e3 + v3;
}

// ---- scatter: XCD-pinned dst-segments --------------------------------------
__global__ __launch_bounds__(256) void k_scatter(const int* __restrict__ src,
                                                 const int* __restrict__ dst,
                                                 int* __restrict__ cursor,
                                                 int* __restrict__ eidx) {
    int b     = blockIdx.x;
    int seg   = b & (NSEG - 1);
    int chunk = b >> 3;
    int e = chunk * 256 + threadIdx.x;
    if (e < NE) {
        int d = dst[e];
        if ((unsigned)d / (unsigned)SEGW == (unsigned)seg) {
            int p = atomicAdd(&cursor[d], 1);
            eidx[p] = src[e];
        }
    }
}

// ---- GEMM1: h1(bf16) = x @ W1  [NN,256]x[256,64], bf16 MFMA ----------------
__global__ __launch_bounds__(256, 4) void k_gemm1(const float* __restrict__ x,
                                                  const unsigned short* __restrict__ wt_g,
                                                  unsigned short* __restrict__ h1) {
    __shared__ unsigned short wt[64 * 264];    // stride 264: 2-way bank alias (free)
    int t = threadIdx.x;
    int w = t >> 6, l = t & 63;
    int row0 = blockIdx.x * 128;

    #pragma unroll
    for (int p = 0; p < 8; ++p) {
        int T   = p * 256 + t;
        int c   = T >> 5;
        int kb8 = T & 31;
        *(us8*)(wt + c * 264 + kb8 * 8) = *(const us8*)(wt_g + c * 256 + kb8 * 8);
    }
    __syncthreads();

    int m = l & 15;
    int g = l >> 4;
    int gr0 = row0 + w * 32 + m;      if (gr0 > NN - 1) gr0 = NN - 1;
    int gr1 = row0 + w * 32 + 16 + m; if (gr1 > NN - 1) gr1 = NN - 1;
    const float* p0 = x + (size_t)gr0 * INF + g * 8;
    const float* p1 = x + (size_t)gr1 * INF + g * 8;

    f32x4 acc[2][4];
    #pragma unroll
    for (int i = 0; i < 2; ++i)
        #pragma unroll
        for (int j = 0; j < 4; ++j) acc[i][j] = (f32x4){0.f, 0.f, 0.f, 0.f};

    #pragma unroll 2
    for (int kb = 0; kb < INF; kb += 32) {
        float4 u0 = *(const float4*)(p0 + kb);
        float4 u1 = *(const float4*)(p0 + kb + 4);
        float4 u2 = *(const float4*)(p1 + kb);
        float4 u3 = *(const float4*)(p1 + kb + 4);
        us8 a0u = { f2bf(u0.x), f2bf(u0.y), f2bf(u0.z), f2bf(u0.w),
                    f2bf(u1.x), f2bf(u1.y), f2bf(u1.z), f2bf(u1.w) };
        us8 a1u = { f2bf(u2.x), f2bf(u2.y), f2bf(u2.z), f2bf(u2.w),
                    f2bf(u3.x), f2bf(u3.y), f2bf(u3.z), f2bf(u3.w) };
        sh8 a0 = __builtin_bit_cast(sh8, a0u);
        sh8 a1 = __builtin_bit_cast(sh8, a1u);
        #pragma unroll
        for (int nt = 0; nt < 4; ++nt) {
            sh8 b = *(const sh8*)(wt + (nt * 16 + m) * 264 + kb + g * 8);
            acc[0][nt] = __builtin_amdgcn_mfma_f32_16x16x32_bf16(a0, b, acc[0][nt], 0, 0, 0);
            acc[1][nt] = __builtin_amdgcn_mfma_f32_16x16x32_bf16(a1, b, acc[1][nt], 0, 0, 0);
        }
    }

    #pragma unroll
    for (int mt = 0; mt < 2; ++mt) {
        #pragma unroll
        for (int r = 0; r < 4; ++r) {
            int gr = row0 + w * 32 + mt * 16 + (l >> 4) * 4 + r;
            if (gr < NN) {
                #pragma unroll
                for (int nt = 0; nt < 4; ++nt)
                    h1[(size_t)gr * HF + nt * 16 + (l & 15)] = f2bf(acc[mt][nt][r]);
            }
        }
    }
}

// ---- Gather layer 1: 8 nodes/wave, 8 lanes/node, lane owns 8 feats ---------
// lane-local acc (no shuffle); 1-deep software pipeline on the edge chain.
// Fused self-loop+bias+relu -> LDS, then block-wide GEMM2 -> h2 (bf16).
__global__ __launch_bounds__(256) void k_gather1(const int* __restrict__ rowptr,
                                                 const int* __restrict__ eidx,
                                                 const float* __restrict__ dinv,
                                                 const unsigned short* __restrict__ h1,
                                                 const float* __restrict__ b1,
                                                 const float* __restrict__ W2,
                                                 unsigned short* __restrict__ h2) {
    __shared__ float w2L[HF * OF];     // 4KB, [k][j]
    __shared__ float hrL[32][HF + 4];  // 8.5KB, stride 68 (bank-spread)
    int t = threadIdx.x;
    *(float4*)(w2L + t * 4) = *(const float4*)(W2 + t * 4);   // 256*4 = 1024 ✓

    int nodeL = t >> 3;           // 0..31: node within block
    int fg    = t & 7;            // feature octet: feats fg*8..fg*8+7
    int v     = blockIdx.x * 32 + nodeL;   // NN = 3125*32 exact
    int beg = rowptr[v], end = rowptr[v + 1];

    float acc[8] = {};
    // 1-deep pipeline: next (eidx, dinv, h1-row) loads overlap current FMAs
    int   s_n = 0;  float w_n = 0.f;  us8 h_n = {};
    if (beg < end) {
        s_n = eidx[beg];
        w_n = dinv[s_n];
        h_n = *(const us8*)(h1 + (size_t)s_n * HF + fg * 8);
    }
    for (int i = beg; i < end; ++i) {
        float w_c = w_n;  us8 h_c = h_n;
        if (i + 1 < end) {
            s_n = eidx[i + 1];
            w_n = dinv[s_n];
            h_n = *(const us8*)(h1 + (size_t)s_n * HF + fg * 8);
        }
        #pragma unroll
        for (int q = 0; q < 8; ++q) acc[q] += w_c * bf2f(h_c[q]);
    }

    // finalize: self-loop + bias + relu -> LDS
    {
        float dv = dinv[v], sl = dv * dv;
        us8 hv = *(const us8*)(h1 + (size_t)v * HF + fg * 8);
        #pragma unroll
        for (int q = 0; q < 8; ++q) {
            float val = dv * acc[q] + sl * bf2f(hv[q]) + b1[fg * 8 + q];
            hrL[nodeL][fg * 8 + q] = val > 0.f ? val : 0.f;
        }
    }
    __syncthreads();

    // block-wide GEMM2: 32 nodes x 16 out-feats = 512 tasks; output bf16
    #pragma unroll
    for (int T = t; T < 512; T += 256) {
        int n = T >> 4, j = T & 15;
        const float* hr = hrL[n];
        float p = 0.f;
        #pragma unroll
        for (int k = 0; k < HF; ++k) p += hr[k] * w2L[k * OF + j];
        h2[(size_t)(blockIdx.x * 32 + n) * OF + j] = f2bf(p);
    }
}

// ---- Gather layer 2: 16 nodes/block, 16 lanes/node, lane owns 1 out-feat ---
// lane-local acc (no shuffle); bf16 h2 gather (32B/edge); fused self-loop+bias.
__global__ __launch_bounds__(256) void k_gather2(const int* __restrict__ rowptr,
                                                 const int* __restrict__ eidx,
                                                 const float* __restrict__ dinv,
                                                 const unsigned short* __restrict__ h2,
                                                 const float* __restrict__ b2,
                                                 float* __restrict__ out) {
    int t     = threadIdx.x;
    int nodeL = t >> 4;           // 0..15
    int j     = t & 15;           // out-feature
    int v     = blockIdx.x * 16 + nodeL;   // NN = 6250*16 exact
    int beg = rowptr[v], end = rowptr[v + 1];

    float acc = 0.f;
    int   s_n = 0;  float w_n = 0.f;  unsigned short h_n = 0;
    if (beg < end) {
        s_n = eidx[beg];
        w_n = dinv[s_n];
        h_n = h2[(size_t)s_n * OF + j];
    }
    for (int i = beg; i < end; ++i) {
        float w_c = w_n;  unsigned short h_c = h_n;
        if (i + 1 < end) {
            s_n = eidx[i + 1];
            w_n = dinv[s_n];
            h_n = h2[(size_t)s_n * OF + j];
        }
        acc += w_c * bf2f(h_c);
    }
    float dv = dinv[v];
    out[(size_t)v * OF + j] = dv * acc + dv * dv * bf2f(h2[(size_t)v * OF + j]) + b2[j];
}

extern "C" void kernel_launch(void* const* d_in, const int* in_sizes, int n_in,
                              void* d_out, int out_size, void* d_ws, size_t ws_size,
                              hipStream_t stream) {
    const float* x   = (const float*)d_in[0];
    const int*   ei  = (const int*)d_in[1];
    const int*   src = ei;            // edge_index[0]
    const int*   dst = ei + NE;       // edge_index[1]
    const float* W1  = (const float*)d_in[2];
    const float* b1  = (const float*)d_in[3];
    const float* W2  = (const float*)d_in[4];
    const float* b2  = (const float*)d_in[5];
    float* out = (float*)d_out;

    // workspace layout (4B units unless noted)
    float* dinv  = (float*)d_ws;                           // [CNTW]
    unsigned short* h1b = (unsigned short*)(dinv + CNTW);  // [NN*64] bf16 (3.2M ints)
    unsigned short* h2b = (unsigned short*)(h1b + (size_t)NN * HF);  // [NN*16] bf16
    int*   cnt   = (int*)(h2b + (size_t)NN * OF + (size_t)NN * OF);  // [CNTW] (h2 region kept 4B-sized)
    int*   rowptr = cnt + CNTW;                            // [100352]
    int*   cursor = rowptr + 100352;                       // [CNTW]
    int*   eidx  = cursor + CNTW;                          // [NE]
    int*   bsum  = eidx + NE;                              // [128]
    unsigned short* wt_g = (unsigned short*)(bsum + 128);  // [64*256] bf16

    // CSR build + norms + W pre-transpose
    k_pre<<<ZBLK + 64, 256, 0, stream>>>(cnt, W1, wt_g);
    k_hist<<<((NE + 255) / 256) * NSEG, 256, 0, stream>>>(dst, cnt);
    k_reduce<<<NBLK, 256, 0, stream>>>(cnt, bsum, dinv);
    k_scan<<<NBLK, 256, 0, stream>>>(cnt, bsum, rowptr, cursor);
    k_scatter<<<((NE + 255) / 256) * NSEG, 256, 0, stream>>>(src, dst, cursor, eidx);

    // layer 1 (+ fused layer-2 GEMM)
    k_gemm1<<<(NN + 127) / 128, 256, 0, stream>>>(x, wt_g, h1b);
    k_gather1<<<NN / 32, 256, 0, stream>>>(rowptr, eidx, dinv, h1b, b1, W2, h2b);

    // layer 2 aggregation
    k_gather2<<<NN / 16, 256, 0, stream>>>(rowptr, eidx, dinv, h2b, b2, out);
}

// Round 12
// 182.711 us; speedup vs baseline: 1.0994x; 1.0465x over previous
//
#include <hip/hip_runtime.h>

namespace {
constexpr int NN  = 100000;   // nodes
constexpr int NE  = 1000000;  // edges
constexpr int INF = 256;
constexpr int HF  = 64;
constexpr int OF  = 16;
constexpr int SCAN_CHUNK = 1024;                       // elems per scan block (256 thr x 4)
constexpr int NBLK = (NN + SCAN_CHUNK - 1) / SCAN_CHUNK; // 98
constexpr int NSEG = 8;       // dst segments, pinned to XCDs via blockIdx%8
constexpr int SEGW = (NN + NSEG - 1) / NSEG;             // 12500 nodes / segment
constexpr int CNTW = 100096;  // padded cnt/cursor width (ints)
constexpr int ZBLK = (CNTW / 4 + 255) / 256;             // 98 zero-blocks
constexpr int GB   = (NN + 127) / 128;                   // 782 gemm1 blocks
constexpr int SB   = ((NE + 255) / 256) * NSEG;          // 31256 scatter blocks
}

typedef __attribute__((ext_vector_type(8))) short     sh8;
typedef __attribute__((ext_vector_type(4))) float     f32x4;
typedef __attribute__((ext_vector_type(8))) unsigned short us8;

__device__ __forceinline__ unsigned short f2bf(float f) {
    unsigned int u = __builtin_bit_cast(unsigned int, f);
    u += 0x7FFFu + ((u >> 16) & 1u);       // round-to-nearest-even
    return (unsigned short)(u >> 16);
}
__device__ __forceinline__ float bf2f(unsigned short s) {
    return __builtin_bit_cast(float, (unsigned int)s << 16);
}

// ---- pre: zero cnt + W1 -> bf16 transposed, one launch ---------------------
__global__ void k_pre(int* __restrict__ cnt, const float* __restrict__ W1,
                      unsigned short* __restrict__ wt_g) {
    int b = blockIdx.x, t = threadIdx.x;
    if (b < ZBLK) {
        int i = (b * 256 + t) * 4;
        if (i < CNTW) *(int4*)(cnt + i) = (int4){0, 0, 0, 0};
    } else {
        int idx = (b - ZBLK) * 256 + t;       // 16384 tasks
        int c = idx >> 8, k = idx & 255;
        wt_g[idx] = f2bf(W1[(size_t)k * HF + c]);
    }
}

// ---- degree histogram (int), XCD-pinned dst segments -----------------------
__global__ void k_hist(const int* __restrict__ dst, int* __restrict__ cnt) {
    int b     = blockIdx.x;
    int seg   = b & (NSEG - 1);
    int chunk = b >> 3;
    int e = chunk * 256 + threadIdx.x;
    if (e < NE) {
        int d = dst[e];
        if ((unsigned)d / (unsigned)SEGW == (unsigned)seg)
            atomicAdd(&cnt[d], 1);
    }
}

// ---- block-reduce of cnt -> bsum, fused dinv = rsqrt(cnt+1) ----------------
__global__ __launch_bounds__(256) void k_reduce(const int* __restrict__ cnt,
                                                int* __restrict__ bsum,
                                                float* __restrict__ dinv) {
    int t = threadIdx.x;
    int i0 = blockIdx.x * SCAN_CHUNK + t * 4;
    int s = 0;
    float dv[4] = {0.f, 0.f, 0.f, 0.f};
    #pragma unroll
    for (int q = 0; q < 4; ++q) {
        if (i0 + q < NN) {
            int c = cnt[i0 + q];
            s += c;
            dv[q] = rsqrtf((float)(c + 1));
        }
    }
    if (i0 + 3 < NN) *(float4*)(dinv + i0) = (float4){dv[0], dv[1], dv[2], dv[3]};
    else { for (int q = 0; q < 4; ++q) if (i0 + q < NN) dinv[i0 + q] = dv[q]; }
    #pragma unroll
    for (int off = 32; off > 0; off >>= 1) s += __shfl_down(s, off);
    __shared__ int wsum[4];
    int lane = t & 63, wid = t >> 6;
    if (lane == 0) wsum[wid] = s;
    __syncthreads();
    if (t == 0) bsum[blockIdx.x] = wsum[0] + wsum[1] + wsum[2] + wsum[3];
}

// ---- scan: each block derives its own prefix from bsum (no partials pass) --
__global__ __launch_bounds__(256) void k_scan(const int* __restrict__ cnt,
                                              const int* __restrict__ bsum,
                                              int* __restrict__ rowptr,
                                              int* __restrict__ cursor) {
    int t = threadIdx.x;
    int b = blockIdx.x;
    int lane = t & 63, wid = t >> 6;

    // per-wave: exclusive prefix of bsum[0..b-1] (NBLK=98 entries, L2-hot)
    int p = 0;
    if (lane < b) p += bsum[lane];
    if (64 + lane < b) p += bsum[64 + lane];
    #pragma unroll
    for (int off = 32; off > 0; off >>= 1) p += __shfl_down(p, off);
    int blockBase = __shfl(p, 0);

    int i0 = b * SCAN_CHUNK + t * 4;
    int v0 = 0, v1 = 0, v2 = 0, v3 = 0;
    if (i0 + 0 < NN) v0 = cnt[i0 + 0];
    if (i0 + 1 < NN) v1 = cnt[i0 + 1];
    if (i0 + 2 < NN) v2 = cnt[i0 + 2];
    if (i0 + 3 < NN) v3 = cnt[i0 + 3];
    int tsum = v0 + v1 + v2 + v3;
    int incl = tsum;
    #pragma unroll
    for (int off = 1; off < 64; off <<= 1) {
        int n = __shfl_up(incl, off);
        if (lane >= off) incl += n;
    }
    __shared__ int wsum[4];
    if (lane == 63) wsum[wid] = incl;
    __syncthreads();
    int woff = 0;
    for (int w = 0; w < wid; ++w) woff += wsum[w];
    int excl = woff + (incl - tsum) + blockBase;
    int e0 = excl, e1 = e0 + v0, e2 = e1 + v1, e3 = e2 + v2;
    if (i0 + 0 < NN) { rowptr[i0 + 0] = e0; cursor[i0 + 0] = e0; }
    if (i0 + 1 < NN) { rowptr[i0 + 1] = e1; cursor[i0 + 1] = e1; }
    if (i0 + 2 < NN) { rowptr[i0 + 2] = e2; cursor[i0 + 2] = e2; }
    if (i0 + 3 < NN) { rowptr[i0 + 3] = e3; cursor[i0 + 3] = e3; }
    if (i0 + 3 == NN - 1) rowptr[NN] = e3 + v3;
}

// ---- FUSED: gemm1 (blocks 0..GB-1) || scatter (blocks GB..GB+SB-1) ---------
// gemm1 and scatter share no data; gemm1 blocks first so they seize the CUs
// and the cheap scatter blocks fill the remaining slots -> overlap on one
// stream without events. Scatter seg = (b-GB)&7 stays a bijective %8 map.
__global__ __launch_bounds__(256, 4) void k_gs(const float* __restrict__ x,
                                               const unsigned short* __restrict__ wt_g,
                                               unsigned short* __restrict__ h1,
                                               const int* __restrict__ src,
                                               const int* __restrict__ dst,
                                               int* __restrict__ cursor,
                                               int* __restrict__ eidx) {
    __shared__ unsigned short wt[64 * 264];    // stride 264: 2-way bank alias (free)
    int b = blockIdx.x;
    int t = threadIdx.x;

    if (b >= GB) {
        // ---- scatter path ----
        int sb    = b - GB;
        int seg   = sb & (NSEG - 1);
        int chunk = sb >> 3;
        int e = chunk * 256 + t;
        if (e < NE) {
            int d = dst[e];
            if ((unsigned)d / (unsigned)SEGW == (unsigned)seg) {
                int p = atomicAdd(&cursor[d], 1);
                eidx[p] = src[e];
            }
        }
        return;
    }

    // ---- gemm1 path ----
    int w = t >> 6, l = t & 63;
    int row0 = b * 128;

    #pragma unroll
    for (int p = 0; p < 8; ++p) {
        int T   = p * 256 + t;
        int c   = T >> 5;
        int kb8 = T & 31;
        *(us8*)(wt + c * 264 + kb8 * 8) = *(const us8*)(wt_g + c * 256 + kb8 * 8);
    }
    __syncthreads();

    int m = l & 15;
    int g = l >> 4;
    int gr0 = row0 + w * 32 + m;      if (gr0 > NN - 1) gr0 = NN - 1;
    int gr1 = row0 + w * 32 + 16 + m; if (gr1 > NN - 1) gr1 = NN - 1;
    const float* p0 = x + (size_t)gr0 * INF + g * 8;
    const float* p1 = x + (size_t)gr1 * INF + g * 8;

    f32x4 acc[2][4];
    #pragma unroll
    for (int i = 0; i < 2; ++i)
        #pragma unroll
        for (int j = 0; j < 4; ++j) acc[i][j] = (f32x4){0.f, 0.f, 0.f, 0.f};

    #pragma unroll 2
    for (int kb = 0; kb < INF; kb += 32) {
        float4 u0 = *(const float4*)(p0 + kb);
        float4 u1 = *(const float4*)(p0 + kb + 4);
        float4 u2 = *(const float4*)(p1 + kb);
        float4 u3 = *(const float4*)(p1 + kb + 4);
        us8 a0u = { f2bf(u0.x), f2bf(u0.y), f2bf(u0.z), f2bf(u0.w),
                    f2bf(u1.x), f2bf(u1.y), f2bf(u1.z), f2bf(u1.w) };
        us8 a1u = { f2bf(u2.x), f2bf(u2.y), f2bf(u2.z), f2bf(u2.w),
                    f2bf(u3.x), f2bf(u3.y), f2bf(u3.z), f2bf(u3.w) };
        sh8 a0 = __builtin_bit_cast(sh8, a0u);
        sh8 a1 = __builtin_bit_cast(sh8, a1u);
        #pragma unroll
        for (int nt = 0; nt < 4; ++nt) {
            sh8 bb = *(const sh8*)(wt + (nt * 16 + m) * 264 + kb + g * 8);
            acc[0][nt] = __builtin_amdgcn_mfma_f32_16x16x32_bf16(a0, bb, acc[0][nt], 0, 0, 0);
            acc[1][nt] = __builtin_amdgcn_mfma_f32_16x16x32_bf16(a1, bb, acc[1][nt], 0, 0, 0);
        }
    }

    #pragma unroll
    for (int mt = 0; mt < 2; ++mt) {
        #pragma unroll
        for (int r = 0; r < 4; ++r) {
            int gr = row0 + w * 32 + mt * 16 + (l >> 4) * 4 + r;
            if (gr < NN) {
                #pragma unroll
                for (int nt = 0; nt < 4; ++nt)
                    h1[(size_t)gr * HF + nt * 16 + (l & 15)] = f2bf(acc[mt][nt][r]);
            }
        }
    }
}

// ---- Gather layer 1: 8 nodes/wave, 8 lanes/node, lane owns 8 feats ---------
// lane-local acc (no shuffle); 1-deep software pipeline on the edge chain.
// Fused self-loop+bias+relu -> LDS, then block-wide GEMM2 -> h2 (bf16).
__global__ __launch_bounds__(256) void k_gather1(const int* __restrict__ rowptr,
                                                 const int* __restrict__ eidx,
                                                 const float* __restrict__ dinv,
                                                 const unsigned short* __restrict__ h1,
                                                 const float* __restrict__ b1,
                                                 const float* __restrict__ W2,
                                                 unsigned short* __restrict__ h2) {
    __shared__ float w2L[HF * OF];     // 4KB, [k][j]
    __shared__ float hrL[32][HF + 4];  // 8.5KB, stride 68 (bank-spread)
    int t = threadIdx.x;
    *(float4*)(w2L + t * 4) = *(const float4*)(W2 + t * 4);   // 256*4 = 1024 ✓

    int nodeL = t >> 3;           // 0..31: node within block
    int fg    = t & 7;            // feature octet: feats fg*8..fg*8+7
    int v     = blockIdx.x * 32 + nodeL;   // NN = 3125*32 exact
    int beg = rowptr[v], end = rowptr[v + 1];

    float acc[8] = {};
    // 1-deep pipeline: next (eidx, dinv, h1-row) loads overlap current FMAs
    int   s_n = 0;  float w_n = 0.f;  us8 h_n = {};
    if (beg < end) {
        s_n = eidx[beg];
        w_n = dinv[s_n];
        h_n = *(const us8*)(h1 + (size_t)s_n * HF + fg * 8);
    }
    for (int i = beg; i < end; ++i) {
        float w_c = w_n;  us8 h_c = h_n;
        if (i + 1 < end) {
            s_n = eidx[i + 1];
            w_n = dinv[s_n];
            h_n = *(const us8*)(h1 + (size_t)s_n * HF + fg * 8);
        }
        #pragma unroll
        for (int q = 0; q < 8; ++q) acc[q] += w_c * bf2f(h_c[q]);
    }

    // finalize: self-loop + bias + relu -> LDS
    {
        float dv = dinv[v], sl = dv * dv;
        us8 hv = *(const us8*)(h1 + (size_t)v * HF + fg * 8);
        #pragma unroll
        for (int q = 0; q < 8; ++q) {
            float val = dv * acc[q] + sl * bf2f(hv[q]) + b1[fg * 8 + q];
            hrL[nodeL][fg * 8 + q] = val > 0.f ? val : 0.f;
        }
    }
    __syncthreads();

    // block-wide GEMM2: 32 nodes x 16 out-feats = 512 tasks; output bf16
    #pragma unroll
    for (int T = t; T < 512; T += 256) {
        int n = T >> 4, j = T & 15;
        const float* hr = hrL[n];
        float p = 0.f;
        #pragma unroll
        for (int k = 0; k < HF; ++k) p += hr[k] * w2L[k * OF + j];
        h2[(size_t)(blockIdx.x * 32 + n) * OF + j] = f2bf(p);
    }
}

// ---- Gather layer 2: 16 nodes/block, 16 lanes/node, lane owns 1 out-feat ---
__global__ __launch_bounds__(256) void k_gather2(const int* __restrict__ rowptr,
                                                 const int* __restrict__ eidx,
                                                 const float* __restrict__ dinv,
                                                 const unsigned short* __restrict__ h2,
                                                 const float* __restrict__ b2,
                                                 float* __restrict__ out) {
    int t     = threadIdx.x;
    int nodeL = t >> 4;           // 0..15
    int j     = t & 15;           // out-feature
    int v     = blockIdx.x * 16 + nodeL;   // NN = 6250*16 exact
    int beg = rowptr[v], end = rowptr[v + 1];

    float acc = 0.f;
    int   s_n = 0;  float w_n = 0.f;  unsigned short h_n = 0;
    if (beg < end) {
        s_n = eidx[beg];
        w_n = dinv[s_n];
        h_n = h2[(size_t)s_n * OF + j];
    }
    for (int i = beg; i < end; ++i) {
        float w_c = w_n;  unsigned short h_c = h_n;
        if (i + 1 < end) {
            s_n = eidx[i + 1];
            w_n = dinv[s_n];
            h_n = h2[(size_t)s_n * OF + j];
        }
        acc += w_c * bf2f(h_c);
    }
    float dv = dinv[v];
    out[(size_t)v * OF + j] = dv * acc + dv * dv * bf2f(h2[(size_t)v * OF + j]) + b2[j];
}

extern "C" void kernel_launch(void* const* d_in, const int* in_sizes, int n_in,
                              void* d_out, int out_size, void* d_ws, size_t ws_size,
                              hipStream_t stream) {
    const float* x   = (const float*)d_in[0];
    const int*   ei  = (const int*)d_in[1];
    const int*   src = ei;            // edge_index[0]
    const int*   dst = ei + NE;       // edge_index[1]
    const float* W1  = (const float*)d_in[2];
    const float* b1  = (const float*)d_in[3];
    const float* W2  = (const float*)d_in[4];
    const float* b2  = (const float*)d_in[5];
    float* out = (float*)d_out;

    // workspace layout (4B units unless noted)
    float* dinv  = (float*)d_ws;                           // [CNTW]
    unsigned short* h1b = (unsigned short*)(dinv + CNTW);  // [NN*64] bf16 (3.2M ints)
    unsigned short* h2b = (unsigned short*)(h1b + (size_t)NN * HF);  // [NN*16] bf16
    int*   cnt   = (int*)(h2b + (size_t)NN * OF + (size_t)NN * OF);  // [CNTW]
    int*   rowptr = cnt + CNTW;                            // [100352]
    int*   cursor = rowptr + 100352;                       // [CNTW]
    int*   eidx  = cursor + CNTW;                          // [NE]
    int*   bsum  = eidx + NE;                              // [128]
    unsigned short* wt_g = (unsigned short*)(bsum + 128);  // [64*256] bf16

    // CSR build + norms + W pre-transpose
    k_pre<<<ZBLK + 64, 256, 0, stream>>>(cnt, W1, wt_g);
    k_hist<<<((NE + 255) / 256) * NSEG, 256, 0, stream>>>(dst, cnt);
    k_reduce<<<NBLK, 256, 0, stream>>>(cnt, bsum, dinv);
    k_scan<<<NBLK, 256, 0, stream>>>(cnt, bsum, rowptr, cursor);

    // gemm1 || scatter in one launch (independent work, overlap on one stream)
    k_gs<<<GB + SB, 256, 0, stream>>>(x, wt_g, h1b, src, dst, cursor, eidx);

    // layer 1 aggregation (+ fused layer-2 GEMM)
    k_gather1<<<NN / 32, 256, 0, stream>>>(rowptr, eidx, dinv, h1b, b1, W2, h2b);

    // layer 2 aggregation
    k_gather2<<<NN / 16, 256, 0, stream>>>(rowptr, eidx, dinv, h2b, b2, out);
}